// Round 18
// baseline (429.168 us; speedup 1.0000x reference)
//
#include <hip/hip_runtime.h>

#define D        128
#define THREADS  512                 // prep / fallback block size
#define B_ROWS   131072
#define GRID_FB  512

typedef __bf16  bf16x8  __attribute__((ext_vector_type(8)));
typedef float   f32x4   __attribute__((ext_vector_type(4)));

#define LOG2E 1.4426950408889634f
// ws layout: [0, 64KB)    wd frags (4096 x 16B): idx = cb*512 + kb*64 + lane
//            [64KB,128KB) wg frags (gamma-folded, bf16-rounded)
//            [128KB,130KB) params f32x4[128]: {sigmoid(log_step), b_in+bias,
//                                              b_gate+beta.Wg^T, colsum(bf16(gamma*Wg))}
#define WS_FRAGS      4096
#define WS_PARAMS_OFF (2 * WS_FRAGS)                    // in 16B units
#define WS_NEEDED     (2 * WS_FRAGS * 16 + 128 * 16)

__device__ __forceinline__ float fexp2(float x) { return __builtin_amdgcn_exp2f(x); }
__device__ __forceinline__ float frcp(float x)  { return __builtin_amdgcn_rcpf(x); }

// tanh(x) = 1 - 2/(e^{2x}+1); inf-safe (e->inf => rcp->0 => 1; e->0 => -1)
__device__ __forceinline__ float fast_tanh(float x) {
    float e = fexp2(x * (2.f * LOG2E));
    return 1.f - 2.f * frcp(e + 1.f);
}
__device__ __forceinline__ float fast_sigmoid(float x) {
    return frcp(1.f + fexp2(-LOG2E * x));
}

#define MFMA(a, b, c) __builtin_amdgcn_mfma_f32_16x16x32_bf16((a), (b), (c), 0, 0, 0)

// ---------------- pre-kernel: fold + repack weights into B-frag order ----------------
__global__ __launch_bounds__(THREADS)
void prep(const float* __restrict__ w_in,   const float* __restrict__ b_in,
          const float* __restrict__ w_rec,  const float* __restrict__ w_gate,
          const float* __restrict__ b_gate, const float* __restrict__ bias,
          const float* __restrict__ log_step,
          const float* __restrict__ gamma,  const float* __restrict__ beta,
          bf16x8* __restrict__ ws)
{
    const int bid = blockIdx.x, tid = threadIdx.x;
    if (bid < 8) {
        // one thread per fragment: t = (cb, kb, lane)
        const int t    = bid * THREADS + tid;     // 0..4095
        const int l    = t & 63;
        const int kb   = (t >> 6) & 7;
        const int w    = (t >> 9) & 7;            // col-block 0..7
        const int hcol = w * 16 + (l & 15);
        const int k    = kb * 32 + ((l >> 4) & 3) * 8;
        bf16x8 fd, fg;
        const float* s1 = (k < 128) ? (w_in + hcol * 128 + k) : (w_rec + hcol * 128 + (k - 128));
        const float* s2 = w_gate + hcol * 256 + k;
        #pragma unroll
        for (int j = 0; j < 8; ++j) {
            fd[j] = (__bf16)s1[j];
            fg[j] = (__bf16)(s2[j] * gamma[k + j]);
        }
        ws[t]            = fd;   // wd
        ws[WS_FRAGS + t] = fg;   // wg (gamma folded)
    } else {
        // params: 4 threads per output column h
        const int h   = tid >> 2;          // 0..127
        const int sub = tid & 3;
        float bacc = 0.f, csum = 0.f;
        const float* wp = w_gate + h * 256 + sub * 64;
        const float* gp = gamma + sub * 64;
        const float* bp = beta  + sub * 64;
        #pragma unroll
        for (int k = 0; k < 64; ++k) {
            const float wv = wp[k];
            bacc += wv * bp[k];
            csum += (float)(__bf16)(wv * gp[k]);   // bitwise-consistent with wg frags
        }
        bacc += __shfl_xor(bacc, 1);
        bacc += __shfl_xor(bacc, 2);
        csum += __shfl_xor(csum, 1);
        csum += __shfl_xor(csum, 2);
        if (sub == 0) {
            f32x4 p;
            p[0] = fast_sigmoid(log_step[h]);
            p[1] = b_in[h] + bias[h];
            p[2] = b_gate[h] + bacc;
            p[3] = csum;
            *((f32x4*)(ws + WS_PARAMS_OFF) + h) = p;
        }
    }
}

// ------- main: barrier-free per-wave 16-row tiles; weights staged in LDS -------
__global__ __launch_bounds__(1024, 4)
void liquid_cell_bf(const float* __restrict__ x, const float* __restrict__ st,
                    const bf16x8* __restrict__ ws, float* __restrict__ out)
{
    __shared__ __align__(16) bf16x8 WL[2 * WS_FRAGS];   // 128 KB: wd | wg, frag order
    __shared__ __align__(16) float  PL[128 * 4];        // 2 KB params

    const int tid = threadIdx.x;
    #pragma unroll
    for (int i = 0; i < 8; ++i) WL[tid + i * 1024] = ws[tid + i * 1024];
    if (tid < 128) ((f32x4*)PL)[tid] = *((const f32x4*)(ws + WS_PARAMS_OFF) + tid);
    __syncthreads();   // the only block-wide barrier in the kernel

    const int lane = tid & 63;
    const int wv   = tid >> 6;          // 0..15
    const int row  = lane & 15;         // A-frag row owned by this lane
    const int q    = lane >> 4;         // 0..3: k-subchunk / C-row group

    // one-hot B fragments for the s-copy MFMA: sel_p[k][n] = (k == p*16 + n)
    bf16x8 sel0, sel1;
    #pragma unroll
    for (int j = 0; j < 8; ++j) {
        const int k = q * 8 + j;
        sel0[j] = (k == row)      ? (__bf16)1.0f : (__bf16)0.0f;
        sel1[j] = (k == row + 16) ? (__bf16)1.0f : (__bf16)0.0f;
    }

    const int wgid = blockIdx.x * 16 + wv;    // 0..4095; tiles wgid, wgid+4096

    #pragma unroll 1
    for (int it = 0; it < 2; ++it) {
        const long tile = (long)wgid + (long)it * 4096;
        const float* xr = x  + (tile * 16 + row) * D + q * 8;
        const float* sr = st + (tile * 16 + row) * D + q * 8;

        // ---- phase A: load + convert directly into A-fragments (registers only) ----
        bf16x8 fx[4], fs[4], ft[4];
        float sum = 0.f, sq = 0.f;
        #pragma unroll
        for (int kb = 0; kb < 4; ++kb) {
            const f32x4 xa = *(const f32x4*)(xr + kb * 32);
            const f32x4 xb = *(const f32x4*)(xr + kb * 32 + 4);
            const f32x4 sa = *(const f32x4*)(sr + kb * 32);
            const f32x4 sb = *(const f32x4*)(sr + kb * 32 + 4);
            #pragma unroll
            for (int j = 0; j < 4; ++j) {
                sum += xa[j] + xb[j] + sa[j] + sb[j];
                sq  += xa[j]*xa[j] + xb[j]*xb[j] + sa[j]*sa[j] + sb[j]*sb[j];
                fx[kb][j]     = (__bf16)xa[j];
                fx[kb][j + 4] = (__bf16)xb[j];
                fs[kb][j]     = (__bf16)sa[j];
                fs[kb][j + 4] = (__bf16)sb[j];
                ft[kb][j]     = (__bf16)fast_tanh(sa[j]);
                ft[kb][j + 4] = (__bf16)fast_tanh(sb[j]);
            }
        }
        // row stats: lanes {row, row+16, row+32, row+48} hold the same tile row
        sum += __shfl_xor(sum, 16);  sq += __shfl_xor(sq, 16);
        sum += __shfl_xor(sum, 32);  sq += __shfl_xor(sq, 32);
        const float mu     = sum * (1.f / 256.f);
        const float rstd   = __builtin_amdgcn_rsqf(sq * (1.f / 256.f) - mu * mu + 1e-5f);
        const float murstd = mu * rstd;

        // stats for the 4 C-rows this lane owns in the epilogue
        float mr4[4], rs4[4];
        #pragma unroll
        for (int rg = 0; rg < 4; ++rg) {
            mr4[rg] = __shfl(murstd, q * 4 + rg);
            rs4[rg] = __shfl(rstd,   q * 4 + rg);
        }

        float* ob = out + (tile * 16 + q * 4) * D + row;

        // ---- per col-block: GEMM2 -> s-copy -> GEMM1 -> epilogue (no barriers) ----
        #pragma unroll
        for (int cb = 0; cb < 8; ++cb) {
            const int fb = cb * 512 + lane;

            f32x4 acc2 = (f32x4)(0.f);
            {
                const bf16x8 w0 = WL[WS_FRAGS + fb +   0];
                const bf16x8 w1 = WL[WS_FRAGS + fb +  64];
                const bf16x8 w2 = WL[WS_FRAGS + fb + 128];
                const bf16x8 w3 = WL[WS_FRAGS + fb + 192];
                const bf16x8 w4 = WL[WS_FRAGS + fb + 256];
                const bf16x8 w5 = WL[WS_FRAGS + fb + 320];
                const bf16x8 w6 = WL[WS_FRAGS + fb + 384];
                const bf16x8 w7 = WL[WS_FRAGS + fb + 448];
                acc2 = MFMA(fx[0], w0, acc2);
                acc2 = MFMA(fx[1], w1, acc2);
                acc2 = MFMA(fx[2], w2, acc2);
                acc2 = MFMA(fx[3], w3, acc2);
                acc2 = MFMA(fs[0], w4, acc2);
                acc2 = MFMA(fs[1], w5, acc2);
                acc2 = MFMA(fs[2], w6, acc2);
                acc2 = MFMA(fs[3], w7, acc2);
            }

            // exact bf16 s at (C-row, col=cb*16+n) via one-hot B
            const f32x4 accs = MFMA(fs[cb >> 1], (cb & 1) ? sel1 : sel0, (f32x4)(0.f));

            f32x4 acc1 = (f32x4)(0.f);
            {
                const bf16x8 v0 = WL[fb +   0];
                const bf16x8 v1 = WL[fb +  64];
                const bf16x8 v2 = WL[fb + 128];
                const bf16x8 v3 = WL[fb + 192];
                const bf16x8 v4 = WL[fb + 256];
                const bf16x8 v5 = WL[fb + 320];
                const bf16x8 v6 = WL[fb + 384];
                const bf16x8 v7 = WL[fb + 448];
                acc1 = MFMA(fx[0], v0, acc1);
                acc1 = MFMA(fx[1], v1, acc1);
                acc1 = MFMA(fx[2], v2, acc1);
                acc1 = MFMA(fx[3], v3, acc1);
                acc1 = MFMA(ft[0], v4, acc1);
                acc1 = MFMA(ft[1], v5, acc1);
                acc1 = MFMA(ft[2], v6, acc1);
                acc1 = MFMA(ft[3], v7, acc1);
            }

            const f32x4 pp = *(const f32x4*)&PL[(cb * 16 + row) * 4];
            #pragma unroll
            for (int rg = 0; rg < 4; ++rg) {
                const float gate   = fast_sigmoid(rs4[rg] * acc2[rg] - mr4[rg] * pp[3] + pp[2]);
                const float target = fast_tanh(acc1[rg] + pp[1]);
                const float blend  = fminf(pp[0] * gate, 1.f);
                const float s      = accs[rg];
                ob[rg * D + cb * 16] = s + blend * (target - s);
            }
        }
    }
}

// ---------------- fallback: exact round-3 kernel (known-good) ----------------
__global__ __launch_bounds__(THREADS, 4)
void liquid_cell_fb(const float* __restrict__ x,      const float* __restrict__ st,
                    const float* __restrict__ w_in,   const float* __restrict__ b_in,
                    const float* __restrict__ w_rec,  const float* __restrict__ w_gate,
                    const float* __restrict__ b_gate, const float* __restrict__ bias,
                    const float* __restrict__ log_step,
                    const float* __restrict__ gamma,  const float* __restrict__ beta,
                    float* __restrict__ out)
{
    __shared__ __align__(16) __bf16 A1[32 * 256];
    __shared__ __align__(16) __bf16 A2[32 * 256];
    __shared__ __align__(16) float  SBUF[32 * 128];

    const int tid  = threadIdx.x;
    const int lane = tid & 63;
    const int wave = tid >> 6;
    const int q    = lane >> 4;
    const int arow = lane & 15;
    const int hcol = wave * 16 + arow;
    const int koff = q * 8;

    const float stepv = fast_sigmoid(log_step[hcol]);
    const float bd    = b_in[hcol] + bias[hcol];
    float       bg    = b_gate[hcol];

    bf16x8 wd[8], wg[8];
    float betaAcc = 0.f;
    #pragma unroll
    for (int kb = 0; kb < 8; ++kb) {
        const int k = kb * 32 + koff;
        const float* s1 = (k < 128) ? (w_in  + hcol * 128 + k)
                                    : (w_rec + hcol * 128 + (k - 128));
        const float* s2 = w_gate + hcol * 256 + k;
        #pragma unroll
        for (int j = 0; j < 8; ++j) {
            wd[kb][j] = (__bf16)s1[j];
            const float wv = s2[j];
            wg[kb][j] = (__bf16)(wv * gamma[k + j]);
            betaAcc  += wv * beta[k + j];
        }
    }
    betaAcc += __shfl_xor(betaAcc, 16);
    betaAcc += __shfl_xor(betaAcc, 32);
    bg += betaAcc;

    const int r    = tid >> 4;
    const int c0   = (tid & 15) * 8;
    const int sw   = (r & 7) << 3;
    const int swf  = (r & 7) << 2;
    const int rsw  = (arow & 7) << 3;

    for (int tile = blockIdx.x; tile < (B_ROWS / 32); tile += GRID_FB) {
        const float* xp = x  + ((long)tile * 32 + r) * D + c0;
        const float* sp = st + ((long)tile * 32 + r) * D + c0;
        const f32x4 xa = *(const f32x4*)xp, xb = *(const f32x4*)(xp + 4);
        const f32x4 sa = *(const f32x4*)sp, sb = *(const f32x4*)(sp + 4);

        float sum = 0.f, sq = 0.f;
        #pragma unroll
        for (int j = 0; j < 4; ++j) {
            sum += xa[j] + xb[j] + sa[j] + sb[j];
            sq  += xa[j]*xa[j] + xb[j]*xb[j] + sa[j]*sa[j] + sb[j]*sb[j];
        }
        #pragma unroll
        for (int m = 1; m < 16; m <<= 1) {
            sum += __shfl_xor(sum, m);
            sq  += __shfl_xor(sq,  m);
        }
        const float mu   = sum * (1.f / 256.f);
        const float rstd = __builtin_amdgcn_rsqf(sq * (1.f / 256.f) - mu * mu + 1e-5f);
        const float nmur = -mu * rstd;

        bf16x8 a1x, a1s, a2x, a2s;
        #pragma unroll
        for (int j = 0; j < 4; ++j) {
            a1x[j]     = (__bf16)xa[j];
            a1x[j + 4] = (__bf16)xb[j];
            a1s[j]     = (__bf16)fast_tanh(sa[j]);
            a1s[j + 4] = (__bf16)fast_tanh(sb[j]);
            a2x[j]     = (__bf16)(xa[j] * rstd + nmur);
            a2x[j + 4] = (__bf16)(xb[j] * rstd + nmur);
            a2s[j]     = (__bf16)(sa[j] * rstd + nmur);
            a2s[j + 4] = (__bf16)(sb[j] * rstd + nmur);
        }

        __syncthreads();
        *(bf16x8*)&A1[(r * 256 +       c0) ^ sw] = a1x;
        *(bf16x8*)&A1[(r * 256 + 128 + c0) ^ sw] = a1s;
        *(bf16x8*)&A2[(r * 256 +       c0) ^ sw] = a2x;
        *(bf16x8*)&A2[(r * 256 + 128 + c0) ^ sw] = a2s;
        *(f32x4*)&SBUF[(r * 128 + c0)     ^ swf] = sa;
        *(f32x4*)&SBUF[(r * 128 + c0 + 4) ^ swf] = sb;
        __syncthreads();

        f32x4 acc1[2], acc2[2];
        #pragma unroll
        for (int ms = 0; ms < 2; ++ms) { acc1[ms] = (f32x4)(0.f); acc2[ms] = (f32x4)(0.f); }

        #pragma unroll
        for (int ms = 0; ms < 2; ++ms) {
            const int base = (ms * 16 + arow) * 256;
            #pragma unroll
            for (int kb = 0; kb < 8; ++kb) {
                bf16x8 a = *(const bf16x8*)&A1[base + ((kb * 32 + koff) ^ rsw)];
                acc1[ms] = MFMA(a, wd[kb], acc1[ms]);
            }
            #pragma unroll
            for (int kb = 0; kb < 8; ++kb) {
                bf16x8 a = *(const bf16x8*)&A2[base + ((kb * 32 + koff) ^ rsw)];
                acc2[ms] = MFMA(a, wg[kb], acc2[ms]);
            }
        }

        const long obase = (long)tile * 32;
        #pragma unroll
        for (int ms = 0; ms < 2; ++ms) {
            #pragma unroll
            for (int rg = 0; rg < 4; ++rg) {
                const int row = ms * 16 + q * 4 + rg;
                const float s      = SBUF[(row * 128 + hcol) ^ ((row & 7) << 2)];
                const float target = fast_tanh(acc1[ms][rg] + bd);
                const float gate   = fast_sigmoid(acc2[ms][rg] + bg);
                const float blend  = fminf(stepv * gate, 1.f);
                out[(obase + row) * D + hcol] = s + blend * (target - s);
            }
        }
    }
}

extern "C" void kernel_launch(void* const* d_in, const int* in_sizes, int n_in,
                              void* d_out, int out_size, void* d_ws, size_t ws_size,
                              hipStream_t stream) {
    const float* x        = (const float*)d_in[0];
    const float* st       = (const float*)d_in[1];
    const float* w_in     = (const float*)d_in[2];
    const float* b_in     = (const float*)d_in[3];
    const float* w_rec    = (const float*)d_in[4];
    const float* w_gate   = (const float*)d_in[5];
    const float* b_gate   = (const float*)d_in[6];
    const float* bias     = (const float*)d_in[7];
    const float* log_step = (const float*)d_in[8];
    const float* gamma    = (const float*)d_in[9];
    const float* beta     = (const float*)d_in[10];
    float* out = (float*)d_out;

    if (ws_size >= (size_t)WS_NEEDED) {
        bf16x8* ws = (bf16x8*)d_ws;
        hipLaunchKernelGGL(prep, dim3(9), dim3(THREADS), 0, stream,
                           w_in, b_in, w_rec, w_gate, b_gate, bias,
                           log_step, gamma, beta, ws);
        hipLaunchKernelGGL(liquid_cell_bf, dim3(256), dim3(1024), 0, stream,
                           x, st, ws, out);
    } else {
        hipLaunchKernelGGL(liquid_cell_fb, dim3(GRID_FB), dim3(THREADS), 0, stream,
                           x, st, w_in, b_in, w_rec, w_gate, b_gate, bias,
                           log_step, gamma, beta, out);
    }
}

// Round 19
// 132.559 us; speedup vs baseline: 3.2376x; 3.2376x over previous
//
#include <hip/hip_runtime.h>

#define D        128
#define M_TILE   32
#define THREADS  512
#define B_ROWS   131072
#define NTILES   (B_ROWS / M_TILE)   // 4096
#define GRID     512
#define NT_PER   (NTILES / GRID)     // 8 tiles per block, exact

typedef __bf16  bf16x8  __attribute__((ext_vector_type(8)));
typedef float   f32x4   __attribute__((ext_vector_type(4)));

#define LOG2E 1.4426950408889634f
// ws layout: [0, 64KB)    wd frags (4096 x 16B): idx = grp*512 + kb*64 + lane
//            [64KB,128KB) wg frags (gamma-folded, bf16-rounded)
//            [128KB,130KB) params f32x4[128]: {sigmoid(log_step), b_in+bias,
//                                              b_gate+beta.Wg^T, colsum(bf16(gamma*Wg))}
#define WS_FRAGS      4096
#define WS_PARAMS_OFF (2 * WS_FRAGS)                    // in 16B units
#define WS_NEEDED     (2 * WS_FRAGS * 16 + 128 * 16)

__device__ __forceinline__ float fexp2(float x) { return __builtin_amdgcn_exp2f(x); }
__device__ __forceinline__ float frcp(float x)  { return __builtin_amdgcn_rcpf(x); }

// tanh(x) = 1 - 2/(e^{2x}+1); inf-safe (e->inf => rcp->0 => 1; e->0 => -1)
__device__ __forceinline__ float fast_tanh(float x) {
    float e = fexp2(x * (2.f * LOG2E));
    return 1.f - 2.f * frcp(e + 1.f);
}
__device__ __forceinline__ float fast_sigmoid(float x) {
    return frcp(1.f + fexp2(-LOG2E * x));
}

#define MFMA(a, b, c) __builtin_amdgcn_mfma_f32_16x16x32_bf16((a), (b), (c), 0, 0, 0)

// ---------------- pre-kernel: fold + repack weights into B-frag order ----------------
__global__ __launch_bounds__(THREADS)
void prep(const float* __restrict__ w_in,   const float* __restrict__ b_in,
          const float* __restrict__ w_rec,  const float* __restrict__ w_gate,
          const float* __restrict__ b_gate, const float* __restrict__ bias,
          const float* __restrict__ log_step,
          const float* __restrict__ gamma,  const float* __restrict__ beta,
          bf16x8* __restrict__ ws)
{
    const int bid = blockIdx.x, tid = threadIdx.x;
    if (bid < 8) {
        // one thread per fragment: t = (grp, kb, lane)
        const int t    = bid * THREADS + tid;     // 0..4095
        const int l    = t & 63;
        const int kb   = (t >> 6) & 7;
        const int w    = (t >> 9) & 7;            // col group 0..7
        const int hcol = w * 16 + (l & 15);
        const int k    = kb * 32 + ((l >> 4) & 3) * 8;
        bf16x8 fd, fg;
        const float* s1 = (k < 128) ? (w_in + hcol * 128 + k) : (w_rec + hcol * 128 + (k - 128));
        const float* s2 = w_gate + hcol * 256 + k;
        #pragma unroll
        for (int j = 0; j < 8; ++j) {
            fd[j] = (__bf16)s1[j];
            fg[j] = (__bf16)(s2[j] * gamma[k + j]);
        }
        ws[t]            = fd;   // wd
        ws[WS_FRAGS + t] = fg;   // wg (gamma folded)
    } else {
        // params: 4 threads per output column h
        const int h   = tid >> 2;          // 0..127
        const int sub = tid & 3;
        float bacc = 0.f, csum = 0.f;
        const float* wp = w_gate + h * 256 + sub * 64;
        const float* gp = gamma + sub * 64;
        const float* bp = beta  + sub * 64;
        #pragma unroll
        for (int k = 0; k < 64; ++k) {
            const float wv = wp[k];
            bacc += wv * bp[k];
            csum += (float)(__bf16)(wv * gp[k]);   // bitwise-consistent with wg frags
        }
        bacc += __shfl_xor(bacc, 1);
        bacc += __shfl_xor(bacc, 2);
        csum += __shfl_xor(csum, 1);
        csum += __shfl_xor(csum, 2);
        if (sub == 0) {
            f32x4 p;
            p[0] = fast_sigmoid(log_step[h]);
            p[1] = b_in[h] + bias[h];
            p[2] = b_gate[h] + bacc;
            p[3] = csum;
            *((f32x4*)(ws + WS_PARAMS_OFF) + h) = p;
        }
    }
}

// ------- main: producer/consumer wave specialization, double-buffered tiles -------
// waves 0-3: build tile t+1 (inputs only, ~56 regs). waves 4-7: fused dual-GEMM +
// epilogue on tile t (weights only, ~100 regs). One barrier per tile.
__global__ __launch_bounds__(THREADS, 4)
void liquid_cell_pc(const float* __restrict__ x, const float* __restrict__ st,
                    const bf16x8* __restrict__ ws, float* __restrict__ out)
{
    __shared__ __align__(16) __bf16 XT[2][M_TILE * 128];  // x,          elem ^= (row&7)<<3
    __shared__ __align__(16) __bf16 TT[2][M_TILE * 128];  // tanh(state)
    __shared__ __align__(16) __bf16 SS[2][M_TILE * 128];  // raw state
    __shared__ float2 MUB[2][M_TILE];                     // {mu*rstd, rstd}

    const int tid  = threadIdx.x;
    const int lane = tid & 63;
    const int wave = tid >> 6;
    const bool producer = (wave < 4);

    // ---- producer indexing: 256 threads cover 32 rows x 16 cols ----
    const int pr  = tid >> 3;              // row 0..31 (producers: tid<256)
    const int pc  = (tid & 7) * 16;        // 16-float col chunk
    const int psw = (pr & 7) << 3;         // write swizzle (bf16-elem units)

    // ---- consumer indexing ----
    const int q    = lane >> 4;
    const int arow = lane & 15;
    const int koff = q * 8;
    const int rsw  = (arow & 7) << 3;
    const int cw   = wave - 4;             // 0..3
    const int g0   = cw, g1 = cw + 4;      // two col groups per consumer wave
    f32x4 pp0, pp1;
    if (!producer) {
        pp0 = *((const f32x4*)(ws + WS_PARAMS_OFF) + (g0 * 16 + arow));
        pp1 = *((const f32x4*)(ws + WS_PARAMS_OFF) + (g1 * 16 + arow));
    }

    const bf16x8* WD = ws;
    const bf16x8* WG = ws + WS_FRAGS;

    // ---- producer phase A: build tile -> buffer b ----
    auto phaseA = [&](int b, long tile) {
        const float* xr = x  + (tile * M_TILE + pr) * D + pc;
        const float* sr = st + (tile * M_TILE + pr) * D + pc;
        f32x4 xv0 = *(const f32x4*)xr,        xv1 = *(const f32x4*)(xr + 4);
        f32x4 xv2 = *(const f32x4*)(xr + 8),  xv3 = *(const f32x4*)(xr + 12);
        f32x4 sv0 = *(const f32x4*)sr,        sv1 = *(const f32x4*)(sr + 4);
        f32x4 sv2 = *(const f32x4*)(sr + 8),  sv3 = *(const f32x4*)(sr + 12);

        float sum = 0.f, sq = 0.f;
        #pragma unroll
        for (int j = 0; j < 4; ++j) {
            sum += xv0[j] + xv1[j] + xv2[j] + xv3[j] + sv0[j] + sv1[j] + sv2[j] + sv3[j];
            sq  += xv0[j]*xv0[j] + xv1[j]*xv1[j] + xv2[j]*xv2[j] + xv3[j]*xv3[j]
                 + sv0[j]*sv0[j] + sv1[j]*sv1[j] + sv2[j]*sv2[j] + sv3[j]*sv3[j];
        }
        // 8 threads per row: reduce over lanes (pr&7)*8 + 0..7
        #pragma unroll
        for (int m = 1; m < 8; m <<= 1) {
            sum += __shfl_xor(sum, m);
            sq  += __shfl_xor(sq,  m);
        }
        const float mu   = sum * (1.f / 256.f);
        const float rstd = __builtin_amdgcn_rsqf(sq * (1.f / 256.f) - mu * mu + 1e-5f);

        bf16x8 fx0, fx1, ft0, ft1, fs0, fs1;
        #pragma unroll
        for (int j = 0; j < 4; ++j) {
            fx0[j] = (__bf16)xv0[j];  fx0[j + 4] = (__bf16)xv1[j];
            fx1[j] = (__bf16)xv2[j];  fx1[j + 4] = (__bf16)xv3[j];
            ft0[j] = (__bf16)fast_tanh(sv0[j]);  ft0[j + 4] = (__bf16)fast_tanh(sv1[j]);
            ft1[j] = (__bf16)fast_tanh(sv2[j]);  ft1[j + 4] = (__bf16)fast_tanh(sv3[j]);
            fs0[j] = (__bf16)sv0[j];  fs0[j + 4] = (__bf16)sv1[j];
            fs1[j] = (__bf16)sv2[j];  fs1[j + 4] = (__bf16)sv3[j];
        }
        *(bf16x8*)&XT[b][(pr * 128 + pc)     ^ psw] = fx0;
        *(bf16x8*)&XT[b][(pr * 128 + pc + 8) ^ psw] = fx1;
        *(bf16x8*)&TT[b][(pr * 128 + pc)     ^ psw] = ft0;
        *(bf16x8*)&TT[b][(pr * 128 + pc + 8) ^ psw] = ft1;
        *(bf16x8*)&SS[b][(pr * 128 + pc)     ^ psw] = fs0;
        *(bf16x8*)&SS[b][(pr * 128 + pc + 8) ^ psw] = fs1;
        if ((tid & 7) == 0) MUB[b][pr] = make_float2(mu * rstd, rstd);
    };

    // ---- consumer: fused dual-GEMM + epilogue for one col group ----
    auto consume = [&](int b, long tile, int g, const f32x4& pp) {
        const int fb = g * 512 + lane;
        bf16x8 fw[8], fv[8];
        #pragma unroll
        for (int kb = 0; kb < 8; ++kb) {
            fw[kb] = WG[fb + kb * 64];
            fv[kb] = WD[fb + kb * 64];
        }
        f32x4 acc2[2], acc1[2];
        acc2[0] = (f32x4)(0.f); acc2[1] = (f32x4)(0.f);
        acc1[0] = (f32x4)(0.f); acc1[1] = (f32x4)(0.f);
        #pragma unroll
        for (int ms = 0; ms < 2; ++ms) {
            const int base = (ms * 16 + arow) * 128;
            #pragma unroll
            for (int kb = 0; kb < 4; ++kb) {
                bf16x8 a = *(const bf16x8*)&XT[b][base + ((kb * 32 + koff) ^ rsw)];
                acc2[ms] = MFMA(a, fw[kb], acc2[ms]);
                acc1[ms] = MFMA(a, fv[kb], acc1[ms]);
            }
            #pragma unroll
            for (int kb = 0; kb < 4; ++kb) {
                bf16x8 s_ = *(const bf16x8*)&SS[b][base + ((kb * 32 + koff) ^ rsw)];
                acc2[ms] = MFMA(s_, fw[kb + 4], acc2[ms]);
                bf16x8 t_ = *(const bf16x8*)&TT[b][base + ((kb * 32 + koff) ^ rsw)];
                acc1[ms] = MFMA(t_, fv[kb + 4], acc1[ms]);
            }
        }
        const int  hcol  = g * 16 + arow;
        const long obase = tile * M_TILE;
        #pragma unroll
        for (int ms = 0; ms < 2; ++ms) {
            #pragma unroll
            for (int rg = 0; rg < 4; ++rg) {
                const int row = ms * 16 + q * 4 + rg;
                const float2 mr = MUB[b][row];
                const float gate   = fast_sigmoid(mr.y * acc2[ms][rg] - mr.x * pp[3] + pp[2]);
                const float s      = (float)SS[b][(row * 128 + hcol) ^ ((row & 7) << 3)];
                const float target = fast_tanh(acc1[ms][rg] + pp[1]);
                const float blend  = fminf(pp[0] * gate, 1.f);
                out[(obase + row) * D + hcol] = s + blend * (target - s);
            }
        }
    };

    // ---- prologue: producers fill buf 0 with tile blockIdx.x ----
    if (producer) phaseA(0, blockIdx.x);
    __syncthreads();

    #pragma unroll 1
    for (int it = 0; it < NT_PER; ++it) {
        const int  buf  = it & 1;
        const long tile = (long)blockIdx.x + (long)it * GRID;
        if (producer) {
            if (it + 1 < NT_PER) phaseA(buf ^ 1, tile + GRID);
        } else {
            consume(buf, tile, g0, pp0);
            consume(buf, tile, g1, pp1);
        }
        __syncthreads();   // buf^1 visible; everyone done with buf
    }
}

// ---------------- fallback: exact round-3 kernel (known-good) ----------------
__global__ __launch_bounds__(THREADS, 4)
void liquid_cell_fb(const float* __restrict__ x,      const float* __restrict__ st,
                    const float* __restrict__ w_in,   const float* __restrict__ b_in,
                    const float* __restrict__ w_rec,  const float* __restrict__ w_gate,
                    const float* __restrict__ b_gate, const float* __restrict__ bias,
                    const float* __restrict__ log_step,
                    const float* __restrict__ gamma,  const float* __restrict__ beta,
                    float* __restrict__ out)
{
    __shared__ __align__(16) __bf16 A1[32 * 256];
    __shared__ __align__(16) __bf16 A2[32 * 256];
    __shared__ __align__(16) float  SBUF[32 * 128];

    const int tid  = threadIdx.x;
    const int lane = tid & 63;
    const int wave = tid >> 6;
    const int q    = lane >> 4;
    const int arow = lane & 15;
    const int hcol = wave * 16 + arow;
    const int koff = q * 8;

    const float stepv = fast_sigmoid(log_step[hcol]);
    const float bd    = b_in[hcol] + bias[hcol];
    float       bg    = b_gate[hcol];

    bf16x8 wd[8], wg[8];
    float betaAcc = 0.f;
    #pragma unroll
    for (int kb = 0; kb < 8; ++kb) {
        const int k = kb * 32 + koff;
        const float* s1 = (k < 128) ? (w_in  + hcol * 128 + k)
                                    : (w_rec + hcol * 128 + (k - 128));
        const float* s2 = w_gate + hcol * 256 + k;
        #pragma unroll
        for (int j = 0; j < 8; ++j) {
            wd[kb][j] = (__bf16)s1[j];
            const float wv = s2[j];
            wg[kb][j] = (__bf16)(wv * gamma[k + j]);
            betaAcc  += wv * beta[k + j];
        }
    }
    betaAcc += __shfl_xor(betaAcc, 16);
    betaAcc += __shfl_xor(betaAcc, 32);
    bg += betaAcc;

    const int r    = tid >> 4;
    const int c0   = (tid & 15) * 8;
    const int sw   = (r & 7) << 3;
    const int swf  = (r & 7) << 2;
    const int rsw  = (arow & 7) << 3;

    for (int tile = blockIdx.x; tile < (B_ROWS / 32); tile += GRID) {
        const float* xp = x  + ((long)tile * 32 + r) * D + c0;
        const float* sp = st + ((long)tile * 32 + r) * D + c0;
        const f32x4 xa = *(const f32x4*)xp, xb = *(const f32x4*)(xp + 4);
        const f32x4 sa = *(const f32x4*)sp, sb = *(const f32x4*)(sp + 4);

        float sum = 0.f, sq = 0.f;
        #pragma unroll
        for (int j = 0; j < 4; ++j) {
            sum += xa[j] + xb[j] + sa[j] + sb[j];
            sq  += xa[j]*xa[j] + xb[j]*xb[j] + sa[j]*sa[j] + sb[j]*sb[j];
        }
        #pragma unroll
        for (int m = 1; m < 16; m <<= 1) {
            sum += __shfl_xor(sum, m);
            sq  += __shfl_xor(sq,  m);
        }
        const float mu   = sum * (1.f / 256.f);
        const float rstd = __builtin_amdgcn_rsqf(sq * (1.f / 256.f) - mu * mu + 1e-5f);
        const float nmur = -mu * rstd;

        bf16x8 a1x, a1s, a2x, a2s;
        #pragma unroll
        for (int j = 0; j < 4; ++j) {
            a1x[j]     = (__bf16)xa[j];
            a1x[j + 4] = (__bf16)xb[j];
            a1s[j]     = (__bf16)fast_tanh(sa[j]);
            a1s[j + 4] = (__bf16)fast_tanh(sb[j]);
            a2x[j]     = (__bf16)(xa[j] * rstd + nmur);
            a2x[j + 4] = (__bf16)(xb[j] * rstd + nmur);
            a2s[j]     = (__bf16)(sa[j] * rstd + nmur);
            a2s[j + 4] = (__bf16)(sb[j] * rstd + nmur);
        }

        __syncthreads();
        *(bf16x8*)&A1[(r * 256 +       c0) ^ sw] = a1x;
        *(bf16x8*)&A1[(r * 256 + 128 + c0) ^ sw] = a1s;
        *(bf16x8*)&A2[(r * 256 +       c0) ^ sw] = a2x;
        *(bf16x8*)&A2[(r * 256 + 128 + c0) ^ sw] = a2s;
        *(f32x4*)&SBUF[(r * 128 + c0)     ^ swf] = sa;
        *(f32x4*)&SBUF[(r * 128 + c0 + 4) ^ swf] = sb;
        __syncthreads();

        f32x4 acc1[2], acc2[2];
        #pragma unroll
        for (int ms = 0; ms < 2; ++ms) { acc1[ms] = (f32x4)(0.f); acc2[ms] = (f32x4)(0.f); }

        #pragma unroll
        for (int ms = 0; ms < 2; ++ms) {
            const int base = (ms * 16 + arow) * 256;
            #pragma unroll
            for (int kb = 0; kb < 8; ++kb) {
                bf16x8 a = *(const bf16x8*)&A1[base + ((kb * 32 + koff) ^ rsw)];
                acc1[ms] = MFMA(a, wd[kb], acc1[ms]);
            }
            #pragma unroll
            for (int kb = 0; kb < 8; ++kb) {
                bf16x8 a = *(const bf16x8*)&A2[base + ((kb * 32 + koff) ^ rsw)];
                acc2[ms] = MFMA(a, wg[kb], acc2[ms]);
            }
        }

        const long obase = (long)tile * 32;
        #pragma unroll
        for (int ms = 0; ms < 2; ++ms) {
            #pragma unroll
            for (int rg = 0; rg < 4; ++rg) {
                const int row = ms * 16 + q * 4 + rg;
                const float s      = SBUF[(row * 128 + hcol) ^ ((row & 7) << 2)];
                const float target = fast_tanh(acc1[ms][rg] + bd);
                const float gate   = fast_sigmoid(acc2[ms][rg] + bg);
                const float blend  = fminf(stepv * gate, 1.f);
                out[(obase + row) * D + hcol] = s + blend * (target - s);
            }
        }
    }
}

extern "C" void kernel_launch(void* const* d_in, const int* in_sizes, int n_in,
                              void* d_out, int out_size, void* d_ws, size_t ws_size,
                              hipStream_t stream) {
    const float* x        = (const float*)d_in[0];
    const float* st       = (const float*)d_in[1];
    const float* w_in     = (const float*)d_in[2];
    const float* b_in     = (const float*)d_in[3];
    const float* w_rec    = (const float*)d_in[4];
    const float* w_gate   = (const float*)d_in[5];
    const float* b_gate   = (const float*)d_in[6];
    const float* bias     = (const float*)d_in[7];
    const float* log_step = (const float*)d_in[8];
    const float* gamma    = (const float*)d_in[9];
    const float* beta     = (const float*)d_in[10];
    float* out = (float*)d_out;

    if (ws_size >= (size_t)WS_NEEDED) {
        bf16x8* ws = (bf16x8*)d_ws;
        hipLaunchKernelGGL(prep, dim3(9), dim3(THREADS), 0, stream,
                           w_in, b_in, w_rec, w_gate, b_gate, bias,
                           log_step, gamma, beta, ws);
        hipLaunchKernelGGL(liquid_cell_pc, dim3(GRID), dim3(THREADS), 0, stream,
                           x, st, ws, out);
    } else {
        hipLaunchKernelGGL(liquid_cell_fb, dim3(GRID), dim3(THREADS), 0, stream,
                           x, st, w_in, b_in, w_rec, w_gate, b_gate, bias,
                           log_step, gamma, beta, out);
    }
}

// Round 20
// 57.232 us; speedup vs baseline: 7.4987x; 2.3162x over previous
//
#include <hip/hip_runtime.h>

#define D        128
#define M_TILE   32
#define THREADS  512
#define B_ROWS   131072
#define NTILES   (B_ROWS / M_TILE)   // 4096
#define GRID     512

typedef __bf16  bf16x8  __attribute__((ext_vector_type(8)));
typedef float   f32x4   __attribute__((ext_vector_type(4)));

#define LOG2E 1.4426950408889634f
// ws layout: [0, 64KB)    wd frags (4096 x 16B): idx = wave*512 + kb*64 + lane
//            [64KB,128KB) wg frags (gamma-folded, bf16-rounded)
//            [128KB,130KB) params f32x4[128]: {sigmoid(log_step), b_in+bias,
//                                              b_gate+beta.Wg^T, colsum(bf16(gamma*Wg))}
#define WS_FRAGS      4096
#define WS_PARAMS_OFF (2 * WS_FRAGS)                    // in 16B units
#define WS_NEEDED     (2 * WS_FRAGS * 16 + 128 * 16)

__device__ __forceinline__ float fexp2(float x) { return __builtin_amdgcn_exp2f(x); }
__device__ __forceinline__ float frcp(float x)  { return __builtin_amdgcn_rcpf(x); }

// tanh(x) = 1 - 2/(e^{2x}+1); inf-safe (e->inf => rcp->0 => 1; e->0 => -1)
__device__ __forceinline__ float fast_tanh(float x) {
    float e = fexp2(x * (2.f * LOG2E));
    return 1.f - 2.f * frcp(e + 1.f);
}
__device__ __forceinline__ float fast_sigmoid(float x) {
    return frcp(1.f + fexp2(-LOG2E * x));
}

// ---------------- pre-kernel: fold + repack weights into B-frag order ----------------
__global__ __launch_bounds__(THREADS)
void prep(const float* __restrict__ w_in,   const float* __restrict__ b_in,
          const float* __restrict__ w_rec,  const float* __restrict__ w_gate,
          const float* __restrict__ b_gate, const float* __restrict__ bias,
          const float* __restrict__ log_step,
          const float* __restrict__ gamma,  const float* __restrict__ beta,
          bf16x8* __restrict__ ws)
{
    const int bid = blockIdx.x, tid = threadIdx.x;
    if (bid < 8) {
        // one thread per fragment: t = (wave, kb, lane)
        const int t    = bid * THREADS + tid;     // 0..4095
        const int l    = t & 63;
        const int kb   = (t >> 6) & 7;
        const int w    = (t >> 9) & 7;
        const int hcol = w * 16 + (l & 15);
        const int k    = kb * 32 + ((l >> 4) & 3) * 8;
        bf16x8 fd, fg;
        const float* s1 = (k < 128) ? (w_in + hcol * 128 + k) : (w_rec + hcol * 128 + (k - 128));
        const float* s2 = w_gate + hcol * 256 + k;
        #pragma unroll
        for (int j = 0; j < 8; ++j) {
            fd[j] = (__bf16)s1[j];
            fg[j] = (__bf16)(s2[j] * gamma[k + j]);
        }
        ws[t]            = fd;   // wd
        ws[WS_FRAGS + t] = fg;   // wg (gamma folded)
    } else {
        // params: 4 threads per output column h
        const int h   = tid >> 2;          // 0..127
        const int sub = tid & 3;
        float bacc = 0.f, csum = 0.f;
        const float* wp = w_gate + h * 256 + sub * 64;
        const float* gp = gamma + sub * 64;
        const float* bp = beta  + sub * 64;
        #pragma unroll
        for (int k = 0; k < 64; ++k) {
            const float wv = wp[k];
            bacc += wv * bp[k];
            csum += (float)(__bf16)(wv * gp[k]);   // bitwise-consistent with wg frags
        }
        bacc += __shfl_xor(bacc, 1);
        bacc += __shfl_xor(bacc, 2);
        csum += __shfl_xor(csum, 1);
        csum += __shfl_xor(csum, 2);
        if (sub == 0) {
            f32x4 p;
            p[0] = fast_sigmoid(log_step[h]);
            p[1] = b_in[h] + bias[h];
            p[2] = b_gate[h] + bacc;
            p[3] = csum;
            *((f32x4*)(ws + WS_PARAMS_OFF) + h) = p;
        }
    }
}

// ------- main kernel: round-12 skeleton, fused dual-GEMM (shared XT reads, 4 MFMA chains) -------
__global__ __launch_bounds__(THREADS, 4)
void liquid_cell_ws(const float* __restrict__ x, const float* __restrict__ st,
                    const bf16x8* __restrict__ ws, float* __restrict__ out)
{
    // 32x128 bf16 half-tiles, XOR-swizzled: elem ^= (row&7)<<3 (16B blocks preserved)
    __shared__ __align__(16) __bf16 XT[M_TILE * 128];   // x
    __shared__ __align__(16) __bf16 TT[M_TILE * 128];   // tanh(state)
    __shared__ __align__(16) __bf16 SS[M_TILE * 128];   // raw state (GEMM2 half + epilogue base)
    __shared__ float2 MUB[M_TILE];                      // per-row {mu*rstd, rstd}

    const int tid  = threadIdx.x;
    const int lane = tid & 63;
    const int wave = tid >> 6;
    const int q    = lane >> 4;
    const int arow = lane & 15;
    const int hcol = wave * 16 + arow;
    const int koff = q * 8;
    const int fbase = wave * 512 + lane;   // frag index: wave*8*64 + lane

    const f32x4 pp = *((const f32x4*)(ws + WS_PARAMS_OFF) + hcol);
    const float stepv = pp[0], bd = pp[1], bg = pp[2], colsum = pp[3];

    const bf16x8* WD = ws;
    const bf16x8* WG = ws + WS_FRAGS;

    const int r    = tid >> 4;              // row within tile, 0..31
    const int c0   = (tid & 15) * 8;        // 8-col chunk
    const int sw   = (r & 7) << 3;          // write swizzle (bf16-elem units)
    const int rsw  = (arow & 7) << 3;       // read swizzle ((ms*16+arow)&7 == arow&7)

    for (int tile = blockIdx.x; tile < NTILES; tile += GRID) {
        // ---- phase A: load + stats + bf16 fragments (no LN applied to the tile) ----
        const float* xp = x  + ((long)tile * M_TILE + r) * D + c0;
        const float* sp = st + ((long)tile * M_TILE + r) * D + c0;
        const f32x4 xa = *(const f32x4*)xp, xb = *(const f32x4*)(xp + 4);
        const f32x4 sa = *(const f32x4*)sp, sb = *(const f32x4*)(sp + 4);

        float sum = 0.f, sq = 0.f;
        #pragma unroll
        for (int j = 0; j < 4; ++j) {
            sum += xa[j] + xb[j] + sa[j] + sb[j];
            sq  += xa[j]*xa[j] + xb[j]*xb[j] + sa[j]*sa[j] + sb[j]*sb[j];
        }
        #pragma unroll
        for (int m = 1; m < 16; m <<= 1) {
            sum += __shfl_xor(sum, m);
            sq  += __shfl_xor(sq,  m);
        }
        const float mu   = sum * (1.f / 256.f);
        const float rstd = __builtin_amdgcn_rsqf(sq * (1.f / 256.f) - mu * mu + 1e-5f);

        bf16x8 fx, ft, fs;
        #pragma unroll
        for (int j = 0; j < 4; ++j) {
            fx[j]     = (__bf16)xa[j];
            fx[j + 4] = (__bf16)xb[j];
            ft[j]     = (__bf16)fast_tanh(sa[j]);
            ft[j + 4] = (__bf16)fast_tanh(sb[j]);
            fs[j]     = (__bf16)sa[j];
            fs[j + 4] = (__bf16)sb[j];
        }

        __syncthreads();   // prior iteration's LDS reads complete
        *(bf16x8*)&XT[(r * 128 + c0) ^ sw] = fx;
        *(bf16x8*)&TT[(r * 128 + c0) ^ sw] = ft;
        *(bf16x8*)&SS[(r * 128 + c0) ^ sw] = fs;
        if ((tid & 15) == 0) MUB[r] = make_float2(mu * rstd, rstd);
        __syncthreads();   // tile + stats visible

        // ---- stream BOTH weight sets (64 regs transient; round-3-proven footprint) ----
        bf16x8 fw[8], fv[8];
        #pragma unroll
        for (int kb = 0; kb < 8; ++kb) {
            fw[kb] = WG[fbase + kb * 64];
            fv[kb] = WD[fbase + kb * 64];
        }

        // ---- fused GEMMs: each XT frag read once, feeds both; 4 independent chains ----
        f32x4 acc2[2], acc1[2];
        acc2[0] = (f32x4)(0.f); acc2[1] = (f32x4)(0.f);
        acc1[0] = (f32x4)(0.f); acc1[1] = (f32x4)(0.f);
        #pragma unroll
        for (int ms = 0; ms < 2; ++ms) {
            const int base = (ms * 16 + arow) * 128;
            #pragma unroll
            for (int kb = 0; kb < 4; ++kb) {
                bf16x8 a = *(const bf16x8*)&XT[base + ((kb * 32 + koff) ^ rsw)];
                acc2[ms] = __builtin_amdgcn_mfma_f32_16x16x32_bf16(a, fw[kb], acc2[ms], 0, 0, 0);
                acc1[ms] = __builtin_amdgcn_mfma_f32_16x16x32_bf16(a, fv[kb], acc1[ms], 0, 0, 0);
            }
            #pragma unroll
            for (int kb = 0; kb < 4; ++kb) {
                bf16x8 s_ = *(const bf16x8*)&SS[base + ((kb * 32 + koff) ^ rsw)];
                acc2[ms] = __builtin_amdgcn_mfma_f32_16x16x32_bf16(s_, fw[kb + 4], acc2[ms], 0, 0, 0);
                bf16x8 t_ = *(const bf16x8*)&TT[base + ((kb * 32 + koff) ^ rsw)];
                acc1[ms] = __builtin_amdgcn_mfma_f32_16x16x32_bf16(t_, fv[kb + 4], acc1[ms], 0, 0, 0);
            }
        }

        // ---- gate + epilogue ----
        const long obase = (long)tile * M_TILE;
        #pragma unroll
        for (int ms = 0; ms < 2; ++ms) {
            #pragma unroll
            for (int rg = 0; rg < 4; ++rg) {
                const int row = ms * 16 + q * 4 + rg;
                const float2 mr = MUB[row];
                const float gate   = fast_sigmoid(mr.y * acc2[ms][rg] - mr.x * colsum + bg);
                const float s      = (float)SS[(row * 128 + hcol) ^ ((row & 7) << 3)];
                const float target = fast_tanh(acc1[ms][rg] + bd);
                const float blend  = fminf(stepv * gate, 1.f);
                out[(obase + row) * D + hcol] = s + blend * (target - s);
            }
        }
    }
}

// ---------------- fallback: exact round-3 kernel (known-good) ----------------
__global__ __launch_bounds__(THREADS, 4)
void liquid_cell_fb(const float* __restrict__ x,      const float* __restrict__ st,
                    const float* __restrict__ w_in,   const float* __restrict__ b_in,
                    const float* __restrict__ w_rec,  const float* __restrict__ w_gate,
                    const float* __restrict__ b_gate, const float* __restrict__ bias,
                    const float* __restrict__ log_step,
                    const float* __restrict__ gamma,  const float* __restrict__ beta,
                    float* __restrict__ out)
{
    __shared__ __align__(16) __bf16 A1[32 * 256];
    __shared__ __align__(16) __bf16 A2[32 * 256];
    __shared__ __align__(16) float  SBUF[32 * 128];

    const int tid  = threadIdx.x;
    const int lane = tid & 63;
    const int wave = tid >> 6;
    const int q    = lane >> 4;
    const int arow = lane & 15;
    const int hcol = wave * 16 + arow;
    const int koff = q * 8;

    const float stepv = fast_sigmoid(log_step[hcol]);
    const float bd    = b_in[hcol] + bias[hcol];
    float       bg    = b_gate[hcol];

    bf16x8 wd[8], wg[8];
    float betaAcc = 0.f;
    #pragma unroll
    for (int kb = 0; kb < 8; ++kb) {
        const int k = kb * 32 + koff;
        const float* s1 = (k < 128) ? (w_in  + hcol * 128 + k)
                                    : (w_rec + hcol * 128 + (k - 128));
        const float* s2 = w_gate + hcol * 256 + k;
        #pragma unroll
        for (int j = 0; j < 8; ++j) {
            wd[kb][j] = (__bf16)s1[j];
            const float wv = s2[j];
            wg[kb][j] = (__bf16)(wv * gamma[k + j]);
            betaAcc  += wv * beta[k + j];
        }
    }
    betaAcc += __shfl_xor(betaAcc, 16);
    betaAcc += __shfl_xor(betaAcc, 32);
    bg += betaAcc;

    const int r    = tid >> 4;
    const int c0   = (tid & 15) * 8;
    const int sw   = (r & 7) << 3;
    const int swf  = (r & 7) << 2;
    const int rsw  = (arow & 7) << 3;

    for (int tile = blockIdx.x; tile < (B_ROWS / 32); tile += GRID) {
        const float* xp = x  + ((long)tile * 32 + r) * D + c0;
        const float* sp = st + ((long)tile * 32 + r) * D + c0;
        const f32x4 xa = *(const f32x4*)xp, xb = *(const f32x4*)(xp + 4);
        const f32x4 sa = *(const f32x4*)sp, sb = *(const f32x4*)(sp + 4);

        float sum = 0.f, sq = 0.f;
        #pragma unroll
        for (int j = 0; j < 4; ++j) {
            sum += xa[j] + xb[j] + sa[j] + sb[j];
            sq  += xa[j]*xa[j] + xb[j]*xb[j] + sa[j]*sa[j] + sb[j]*sb[j];
        }
        #pragma unroll
        for (int m = 1; m < 16; m <<= 1) {
            sum += __shfl_xor(sum, m);
            sq  += __shfl_xor(sq,  m);
        }
        const float mu   = sum * (1.f / 256.f);
        const float rstd = __builtin_amdgcn_rsqf(sq * (1.f / 256.f) - mu * mu + 1e-5f);
        const float nmur = -mu * rstd;

        bf16x8 a1x, a1s, a2x, a2s;
        #pragma unroll
        for (int j = 0; j < 4; ++j) {
            a1x[j]     = (__bf16)xa[j];
            a1x[j + 4] = (__bf16)xb[j];
            a1s[j]     = (__bf16)fast_tanh(sa[j]);
            a1s[j + 4] = (__bf16)fast_tanh(sb[j]);
            a2x[j]     = (__bf16)(xa[j] * rstd + nmur);
            a2x[j + 4] = (__bf16)(xb[j] * rstd + nmur);
            a2s[j]     = (__bf16)(sa[j] * rstd + nmur);
            a2s[j + 4] = (__bf16)(sb[j] * rstd + nmur);
        }

        __syncthreads();
        *(bf16x8*)&A1[(r * 256 +       c0) ^ sw] = a1x;
        *(bf16x8*)&A1[(r * 256 + 128 + c0) ^ sw] = a1s;
        *(bf16x8*)&A2[(r * 256 +       c0) ^ sw] = a2x;
        *(bf16x8*)&A2[(r * 256 + 128 + c0) ^ sw] = a2s;
        *(f32x4*)&SBUF[(r * 128 + c0)     ^ swf] = sa;
        *(f32x4*)&SBUF[(r * 128 + c0 + 4) ^ swf] = sb;
        __syncthreads();

        f32x4 acc1[2], acc2[2];
        #pragma unroll
        for (int ms = 0; ms < 2; ++ms) { acc1[ms] = (f32x4)(0.f); acc2[ms] = (f32x4)(0.f); }

        #pragma unroll
        for (int ms = 0; ms < 2; ++ms) {
            const int base = (ms * 16 + arow) * 256;
            #pragma unroll
            for (int kb = 0; kb < 8; ++kb) {
                bf16x8 a = *(const bf16x8*)&A1[base + ((kb * 32 + koff) ^ rsw)];
                acc1[ms] = __builtin_amdgcn_mfma_f32_16x16x32_bf16(a, wd[kb], acc1[ms], 0, 0, 0);
            }
            #pragma unroll
            for (int kb = 0; kb < 8; ++kb) {
                bf16x8 a = *(const bf16x8*)&A2[base + ((kb * 32 + koff) ^ rsw)];
                acc2[ms] = __builtin_amdgcn_mfma_f32_16x16x32_bf16(a, wg[kb], acc2[ms], 0, 0, 0);
            }
        }

        const long obase = (long)tile * 32;
        #pragma unroll
        for (int ms = 0; ms < 2; ++ms) {
            #pragma unroll
            for (int rg = 0; rg < 4; ++rg) {
                const int row = ms * 16 + q * 4 + rg;
                const float s      = SBUF[(row * 128 + hcol) ^ ((row & 7) << 2)];
                const float target = fast_tanh(acc1[ms][rg] + bd);
                const float gate   = fast_sigmoid(acc2[ms][rg] + bg);
                const float blend  = fminf(stepv * gate, 1.f);
                out[(obase + row) * D + hcol] = s + blend * (target - s);
            }
        }
    }
}

extern "C" void kernel_launch(void* const* d_in, const int* in_sizes, int n_in,
                              void* d_out, int out_size, void* d_ws, size_t ws_size,
                              hipStream_t stream) {
    const float* x        = (const float*)d_in[0];
    const float* st       = (const float*)d_in[1];
    const float* w_in     = (const float*)d_in[2];
    const float* b_in     = (const float*)d_in[3];
    const float* w_rec    = (const float*)d_in[4];
    const float* w_gate   = (const float*)d_in[5];
    const float* b_gate   = (const float*)d_in[6];
    const float* bias     = (const float*)d_in[7];
    const float* log_step = (const float*)d_in[8];
    const float* gamma    = (const float*)d_in[9];
    const float* beta     = (const float*)d_in[10];
    float* out = (float*)d_out;

    if (ws_size >= (size_t)WS_NEEDED) {
        bf16x8* ws = (bf16x8*)d_ws;
        hipLaunchKernelGGL(prep, dim3(9), dim3(THREADS), 0, stream,
                           w_in, b_in, w_rec, w_gate, b_gate, bias,
                           log_step, gamma, beta, ws);
        hipLaunchKernelGGL(liquid_cell_ws, dim3(GRID), dim3(THREADS), 0, stream,
                           x, st, ws, out);
    } else {
        hipLaunchKernelGGL(liquid_cell_fb, dim3(GRID), dim3(THREADS), 0, stream,
                           x, st, w_in, b_in, w_rec, w_gate, b_gate, bias,
                           log_step, gamma, beta, out);
    }
}